// Round 9
// baseline (273.486 us; speedup 1.0000x reference)
//
#include <hip/hip_runtime.h>
#include <hip/hip_bf16.h>

// Sorted segment-sum, segment-ownership (no atomics, no memset).
// R8 structure (NT dword loads, A/B 2-deep pipeline, readlane walk, LDS
// output tile + phase-separated 1KB NT dwordx4 burst) with DOUBLED
// OCCUPANCY: SEGS_PER_WAVE 32 (8KB tile/wave), 4 waves per 256-thread
// block -> 32KB LDS/block -> 5 blocks/CU = 20 waves/CU (was 10).

#define SEGS_PER_WAVE 32
#define D_EMBED 64
#define BATCH 16

typedef float f32x4 __attribute__((ext_vector_type(4)));

__device__ inline int lower_bound(const int* __restrict__ idx, int n, int v) {
    int lo = 0, hi = n;
    while (lo < hi) {
        int mid = (lo + hi) >> 1;
        if (idx[mid] < v) lo = mid + 1; else hi = mid;
    }
    return lo;
}

__global__ __launch_bounds__(256) void seg_sum_kernel(
        const float* __restrict__ emb,
        const int*   __restrict__ idx,
        float*       __restrict__ out,
        int n_frag, int n_seg) {
    __shared__ float lds[4][SEGS_PER_WAVE * D_EMBED];   // 4 waves x 8KB

    const int gtid = blockIdx.x * blockDim.x + threadIdx.x;
    const int wave = gtid >> 6;
    const int lane = threadIdx.x & 63;                  // = dim
    float* tile = lds[(threadIdx.x >> 6) & 3];          // this wave's tile

    const int s0 = wave * SEGS_PER_WAVE;
    if (s0 >= n_seg) return;
    const int s1 = min(s0 + SEGS_PER_WAVE, n_seg);

    int       f  = lower_bound(idx, n_frag, s0);
    const int f1 = lower_bound(idx, n_frag, s1);

    int   cur = -1;    // segment currently accumulating (-1 = none yet)
    int   nxt = s0;    // next segment id still needing its tile row written
    float acc = 0.0f;

    auto BOUNDARY = [&](int s) {
        if (cur >= 0) { tile[(cur - s0) * D_EMBED + lane] = acc; nxt = cur + 1; }
        for (int z = nxt; z < s; ++z)                   // empty segments -> zeros
            tile[(z - s0) * D_EMBED + lane] = 0.0f;
        cur = s; nxt = s; acc = 0.0f;
    };

    float vA[BATCH], vB[BATCH];
    int   mA = 0, mB = 0;

    auto LOAD_A = [&](long fb) {
        mA = idx[fb + (lane & (BATCH - 1))];            // one 64B line, broadcast
        const float* base = emb + fb * D_EMBED + lane;
#pragma unroll
        for (int j = 0; j < BATCH; ++j)
            vA[j] = __builtin_nontemporal_load(base + j * D_EMBED);
    };
    auto LOAD_B = [&](long fb) {
        mB = idx[fb + (lane & (BATCH - 1))];
        const float* base = emb + fb * D_EMBED + lane;
#pragma unroll
        for (int j = 0; j < BATCH; ++j)
            vB[j] = __builtin_nontemporal_load(base + j * D_EMBED);
    };
    auto WALK = [&](const float* v, int mseg) {
#pragma unroll
        for (int j = 0; j < BATCH; ++j) {
            int s = __builtin_amdgcn_readlane(mseg, j);
            if (s != cur) BOUNDARY(s);                  // wave-uniform
            acc += v[j];
        }
    };

    const int nfull = (f1 - f) >> 4;                    // full 16-frag batches
    long fcur = f;
    int  b = 0;
    if (nfull > 0) LOAD_A(fcur);
    while (b < nfull) {
        if (b + 1 < nfull) LOAD_B(fcur + BATCH);        // prefetch before walk
        WALK(vA, mA);
        fcur += BATCH; ++b;
        if (b >= nfull) break;
        if (b + 1 < nfull) LOAD_A(fcur + BATCH);
        WALK(vB, mB);
        fcur += BATCH; ++b;
    }

    // tail: < 16 fragments
    for (long ff = (long)f + (long)nfull * BATCH; ff < f1; ++ff) {
        int   s = idx[ff];                              // uniform
        float v = emb[ff * D_EMBED + lane];
        if (s != cur) BOUNDARY(s);
        acc += v;
    }

    // final flush + trailing empty rows
    BOUNDARY(s1);

    // ---- phase-separated burst write: contiguous slab, 1KB per instr ----
    const int nvec = (s1 - s0) * D_EMBED / 4;           // f32x4 count (512 full)
    const f32x4* tp = (const f32x4*)tile;
    f32x4*       op = (f32x4*)(out + (long)s0 * D_EMBED);
#pragma unroll 4
    for (int i = lane; i < nvec; i += 64)               // 8 iters
        __builtin_nontemporal_store(tp[i], op + i);
}

extern "C" void kernel_launch(void* const* d_in, const int* in_sizes, int n_in,
                              void* d_out, int out_size, void* d_ws, size_t ws_size,
                              hipStream_t stream) {
    const float* emb = (const float*)d_in[0];
    const int*   idx = (const int*)d_in[1];
    float*       out = (float*)d_out;

    const int n_frag = in_sizes[0] / D_EMBED;   // 4,000,000
    const int n_seg  = out_size / D_EMBED;      // 1,000,000

    const int n_waves  = (n_seg + SEGS_PER_WAVE - 1) / SEGS_PER_WAVE;  // 31250
    const int block    = 256;                   // 4 waves / block
    const int waves_pb = block / 64;
    const int grid     = (n_waves + waves_pb - 1) / waves_pb;

    seg_sum_kernel<<<grid, block, 0, stream>>>(emb, idx, out, n_frag, n_seg);
}

// Round 10
// 258.175 us; speedup vs baseline: 1.0593x; 1.0593x over previous
//
#include <hip/hip_runtime.h>
#include <hip/hip_bf16.h>

// Sorted segment-sum, segment-ownership (no atomics, no memset, NO LDS).
// R8 load/walk (16 NT dword loads per 16-frag batch, A/B 2-deep pipeline,
// readlane-driven boundary walk, register accumulator, lane = dim,
// SEGS_PER_WAVE=64). STORE: at each boundary, 4 __shfl gather acc into
// f32x4 on lanes 0-15, then ONE 256B NT dwordx4 store — R8's 16B/lane NT
// packet width without the 16KB tile or the serial end-of-wave burst.
// Stores interleave with the read stream; occupancy is VGPR-bound (~2x R8).

#define SEGS_PER_WAVE 64
#define D_EMBED 64
#define BATCH 16

typedef float f32x4 __attribute__((ext_vector_type(4)));

__device__ inline int lower_bound(const int* __restrict__ idx, int n, int v) {
    int lo = 0, hi = n;
    while (lo < hi) {
        int mid = (lo + hi) >> 1;
        if (idx[mid] < v) lo = mid + 1; else hi = mid;
    }
    return lo;
}

__global__ __launch_bounds__(256) void seg_sum_kernel(
        const float* __restrict__ emb,
        const int*   __restrict__ idx,
        float*       __restrict__ out,
        int n_frag, int n_seg) {
    const int gtid = blockIdx.x * blockDim.x + threadIdx.x;
    const int wave = gtid >> 6;
    const int lane = threadIdx.x & 63;              // = dim

    const int s0 = wave * SEGS_PER_WAVE;
    if (s0 >= n_seg) return;
    const int s1 = min(s0 + SEGS_PER_WAVE, n_seg);

    int       f  = lower_bound(idx, n_frag, s0);
    const int f1 = lower_bound(idx, n_frag, s1);

    const f32x4 ZERO4 = {0.f, 0.f, 0.f, 0.f};
    int   cur = -1;    // segment currently accumulating (-1 = none yet)
    int   nxt = s0;    // next segment id still needing its output written
    float acc = 0.0f;

    auto BOUNDARY = [&](int s) {
        if (cur >= 0) {
            // gather: lane r<16 collects dims 4r..4r+3 of acc
            float t0 = __shfl(acc, 4 * lane + 0);
            float t1 = __shfl(acc, 4 * lane + 1);
            float t2 = __shfl(acc, 4 * lane + 2);
            float t3 = __shfl(acc, 4 * lane + 3);
            if (lane < 16) {
                f32x4 t = {t0, t1, t2, t3};
                __builtin_nontemporal_store(t, (f32x4*)(out + (long)cur * D_EMBED) + lane);
            }
            nxt = cur + 1;
        }
        for (int z = nxt; z < s; ++z)               // empty segments -> zeros
            if (lane < 16)
                __builtin_nontemporal_store(ZERO4, (f32x4*)(out + (long)z * D_EMBED) + lane);
        cur = s; nxt = s; acc = 0.0f;
    };

    float vA[BATCH], vB[BATCH];
    int   mA = 0, mB = 0;

    auto LOAD_A = [&](long fb) {
        mA = idx[fb + (lane & (BATCH - 1))];        // one 64B line, broadcast
        const float* base = emb + fb * D_EMBED + lane;
#pragma unroll
        for (int j = 0; j < BATCH; ++j)
            vA[j] = __builtin_nontemporal_load(base + j * D_EMBED);
    };
    auto LOAD_B = [&](long fb) {
        mB = idx[fb + (lane & (BATCH - 1))];
        const float* base = emb + fb * D_EMBED + lane;
#pragma unroll
        for (int j = 0; j < BATCH; ++j)
            vB[j] = __builtin_nontemporal_load(base + j * D_EMBED);
    };
    auto WALK = [&](const float* v, int mseg) {
#pragma unroll
        for (int j = 0; j < BATCH; ++j) {
            int s = __builtin_amdgcn_readlane(mseg, j);
            if (s != cur) BOUNDARY(s);              // wave-uniform, ~1-in-4
            acc += v[j];
        }
    };

    const int nfull = (f1 - f) >> 4;                // full 16-frag batches
    long fcur = f;
    int  b = 0;
    if (nfull > 0) LOAD_A(fcur);
    while (b < nfull) {
        if (b + 1 < nfull) LOAD_B(fcur + BATCH);    // prefetch before walk
        WALK(vA, mA);
        fcur += BATCH; ++b;
        if (b >= nfull) break;
        if (b + 1 < nfull) LOAD_A(fcur + BATCH);
        WALK(vB, mB);
        fcur += BATCH; ++b;
    }

    // tail: < 16 fragments
    for (long ff = (long)f + (long)nfull * BATCH; ff < f1; ++ff) {
        int   s = idx[ff];                          // uniform
        float v = emb[ff * D_EMBED + lane];
        if (s != cur) BOUNDARY(s);
        acc += v;
    }

    // final flush + trailing empty segments
    BOUNDARY(s1);
}

extern "C" void kernel_launch(void* const* d_in, const int* in_sizes, int n_in,
                              void* d_out, int out_size, void* d_ws, size_t ws_size,
                              hipStream_t stream) {
    const float* emb = (const float*)d_in[0];
    const int*   idx = (const int*)d_in[1];
    float*       out = (float*)d_out;

    const int n_frag = in_sizes[0] / D_EMBED;   // 4,000,000
    const int n_seg  = out_size / D_EMBED;      // 1,000,000

    const int n_waves  = (n_seg + SEGS_PER_WAVE - 1) / SEGS_PER_WAVE;  // 15625
    const int block    = 256;                   // 4 waves / block
    const int waves_pb = block / 64;
    const int grid     = (n_waves + waves_pb - 1) / waves_pb;

    seg_sum_kernel<<<grid, block, 0, stream>>>(emb, idx, out, n_frag, n_seg);
}

// Round 11
// 232.626 us; speedup vs baseline: 1.1756x; 1.1098x over previous
//
#include <hip/hip_runtime.h>
#include <hip/hip_bf16.h>

// Sorted segment-sum, segment-ownership (no atomics, no memset).
// FINAL (= R8, best of ladder: 546 -> 232.5 us):
//  - one wave per 64 contiguous segments; binary search exact fragment span
//  - 16-frag batches: 1 coalesced idx line + 16 NT dword loads, A/B 2-deep
//    software pipeline; readlane-driven boundary walk (branches resolve from
//    registers, loop control decoupled from memory)
//  - boundary flushes write a per-wave 16KB LDS tile; end-of-wave burst of
//    16 x 1KB NT dwordx4 stores (full-line merging, phase-separated)
//  - NT policy on both zero-reuse streams (no L2 pollution)
// Ladder: naive-atomic 546 | seg-own 657 | reg-walk 294 | pipe 287.5 |
//         NT 253.6 | LDS-tile burst 232.5 | (32-seg 273.5, shfl-store 258.2)

#define SEGS_PER_WAVE 64
#define D_EMBED 64
#define BATCH 16

typedef float f32x4 __attribute__((ext_vector_type(4)));

__device__ inline int lower_bound(const int* __restrict__ idx, int n, int v) {
    int lo = 0, hi = n;
    while (lo < hi) {
        int mid = (lo + hi) >> 1;
        if (idx[mid] < v) lo = mid + 1; else hi = mid;
    }
    return lo;
}

__global__ __launch_bounds__(64) void seg_sum_kernel(
        const float* __restrict__ emb,
        const int*   __restrict__ idx,
        float*       __restrict__ out,
        int n_frag, int n_seg) {
    __shared__ float tile[SEGS_PER_WAVE * D_EMBED];   // 16 KB, one wave/block

    const int wave = blockIdx.x;
    const int lane = threadIdx.x;                     // 0..63, = dim

    const int s0 = wave * SEGS_PER_WAVE;
    if (s0 >= n_seg) return;
    const int s1 = min(s0 + SEGS_PER_WAVE, n_seg);

    int       f  = lower_bound(idx, n_frag, s0);
    const int f1 = lower_bound(idx, n_frag, s1);

    int   cur = -1;    // segment currently accumulating (-1 = none yet)
    int   nxt = s0;    // next segment id still needing its tile row written
    float acc = 0.0f;

    auto BOUNDARY = [&](int s) {
        if (cur >= 0) { tile[(cur - s0) * D_EMBED + lane] = acc; nxt = cur + 1; }
        for (int z = nxt; z < s; ++z)                 // empty segments -> zeros
            tile[(z - s0) * D_EMBED + lane] = 0.0f;
        cur = s; nxt = s; acc = 0.0f;
    };

    float vA[BATCH], vB[BATCH];
    int   mA = 0, mB = 0;

    auto LOAD_A = [&](long fb) {
        mA = idx[fb + (lane & (BATCH - 1))];          // one 64B line, broadcast
        const float* base = emb + fb * D_EMBED + lane;
#pragma unroll
        for (int j = 0; j < BATCH; ++j)
            vA[j] = __builtin_nontemporal_load(base + j * D_EMBED);
    };
    auto LOAD_B = [&](long fb) {
        mB = idx[fb + (lane & (BATCH - 1))];
        const float* base = emb + fb * D_EMBED + lane;
#pragma unroll
        for (int j = 0; j < BATCH; ++j)
            vB[j] = __builtin_nontemporal_load(base + j * D_EMBED);
    };
    auto WALK = [&](const float* v, int mseg) {
#pragma unroll
        for (int j = 0; j < BATCH; ++j) {
            int s = __builtin_amdgcn_readlane(mseg, j);
            if (s != cur) BOUNDARY(s);                // wave-uniform, ~1-in-4
            acc += v[j];
        }
    };

    const int nfull = (f1 - f) >> 4;                  // full 16-frag batches
    long fcur = f;
    int  b = 0;
    if (nfull > 0) LOAD_A(fcur);
    while (b < nfull) {
        if (b + 1 < nfull) LOAD_B(fcur + BATCH);      // prefetch before walk
        WALK(vA, mA);
        fcur += BATCH; ++b;
        if (b >= nfull) break;
        if (b + 1 < nfull) LOAD_A(fcur + BATCH);
        WALK(vB, mB);
        fcur += BATCH; ++b;
    }

    // tail: < 16 fragments
    for (long ff = (long)f + (long)nfull * BATCH; ff < f1; ++ff) {
        int   s = idx[ff];                            // uniform
        float v = emb[ff * D_EMBED + lane];
        if (s != cur) BOUNDARY(s);
        acc += v;
    }

    // final flush + trailing empty rows
    BOUNDARY(s1);

    // ---- phase-separated burst write: contiguous slab, 1KB per instr ----
    const int nvec = (s1 - s0) * D_EMBED / 4;         // f32x4 count (1024 full)
    const f32x4* tp = (const f32x4*)tile;
    f32x4*       op = (f32x4*)(out + (long)s0 * D_EMBED);
#pragma unroll 4
    for (int i = lane; i < nvec; i += 64)             // 16 iters: 64 lanes x 16B
        __builtin_nontemporal_store(tp[i], op + i);
}

extern "C" void kernel_launch(void* const* d_in, const int* in_sizes, int n_in,
                              void* d_out, int out_size, void* d_ws, size_t ws_size,
                              hipStream_t stream) {
    const float* emb = (const float*)d_in[0];
    const int*   idx = (const int*)d_in[1];
    float*       out = (float*)d_out;

    const int n_frag = in_sizes[0] / D_EMBED;   // 4,000,000
    const int n_seg  = out_size / D_EMBED;      // 1,000,000

    const int n_waves = (n_seg + SEGS_PER_WAVE - 1) / SEGS_PER_WAVE;  // 15625
    seg_sum_kernel<<<n_waves, 64, 0, stream>>>(emb, idx, out, n_frag, n_seg);
}